// Round 1
// baseline (241.560 us; speedup 1.0000x reference)
//
#include <hip/hip_runtime.h>

// VQ argmin: x [16,64,64,64] NCHW fp32, codebook [1024,64] fp32.
// N = 16*64*64 = 65536 rows (b,h,w), D=64 channels, K=1024 codes.
// dist = ||e_k||^2 - 2*x.e_k  (||x||^2 dropped: row-constant, argmin-invariant)

#define K_CODES 1024
#define D_DIM   64
#define HW      4096   // 64*64

__global__ __launch_bounds__(256) void enorm_kernel(const float* __restrict__ cb,
                                                    float* __restrict__ enorm) {
    int k = blockIdx.x * 256 + threadIdx.x;   // grid = 4 x 256 -> 1024
    const float4* row = (const float4*)(cb + (size_t)k * D_DIM);
    float s = 0.f;
#pragma unroll
    for (int i = 0; i < D_DIM / 4; ++i) {
        float4 v = row[i];
        s = fmaf(v.x, v.x, s);
        s = fmaf(v.y, v.y, s);
        s = fmaf(v.z, v.z, s);
        s = fmaf(v.w, v.w, s);
    }
    enorm[k] = s;
}

// Block = 1024 threads: 256 rows x 4 K-quarters. Each thread: one row, 256 codes.
// x row (64 fp32) lives in VGPRs; codebook k is wave-uniform -> scalar loads.
__global__ __launch_bounds__(1024) void vq_kernel(const float* __restrict__ x,
                                                  const float* __restrict__ cb,
                                                  const float* __restrict__ enorm,
                                                  int* __restrict__ out) {
    const int tid = threadIdx.x;
    const int row_local = tid & 255;
    // tid>>8 is uniform within each wave (wave=64 consecutive tids); make it
    // explicitly uniform so k stays in SGPRs -> s_load for codebook.
    const int quarter = __builtin_amdgcn_readfirstlane(tid >> 8);
    const int n = blockIdx.x * 256 + row_local;
    const int b = n >> 12;          // n / 4096
    const int hw = n & (HW - 1);

    // Gather this row's 64 channels (stride HW floats). Coalesced across lanes.
    const float* xb = x + (size_t)b * D_DIM * HW + hw;
    float xv[D_DIM];
#pragma unroll
    for (int d = 0; d < D_DIM; ++d) xv[d] = xb[(size_t)d * HW];

    float best = __builtin_inff();
    int bestk = 0;
    const int kbase = quarter * (K_CODES / 4);

    for (int kk = 0; kk < K_CODES / 4; kk += 4) {
        const int k = kbase + kk;                   // wave-uniform
        const float* __restrict__ e = cb + (size_t)k * D_DIM;
        float a0 = 0.f, a1 = 0.f, a2 = 0.f, a3 = 0.f;
#pragma unroll
        for (int d = 0; d < D_DIM; ++d) {
            const float xd = xv[d];
            a0 = fmaf(e[d],             xd, a0);
            a1 = fmaf(e[D_DIM + d],     xd, a1);
            a2 = fmaf(e[2 * D_DIM + d], xd, a2);
            a3 = fmaf(e[3 * D_DIM + d], xd, a3);
        }
        const float d0 = fmaf(-2.f, a0, enorm[k]);
        const float d1 = fmaf(-2.f, a1, enorm[k + 1]);
        const float d2 = fmaf(-2.f, a2, enorm[k + 2]);
        const float d3 = fmaf(-2.f, a3, enorm[k + 3]);
        // strict < and ascending k -> numpy argmin first-occurrence semantics
        if (d0 < best) { best = d0; bestk = k; }
        if (d1 < best) { best = d1; bestk = k + 1; }
        if (d2 < best) { best = d2; bestk = k + 2; }
        if (d3 < best) { best = d3; bestk = k + 3; }
    }

    // Combine the 4 K-quarters per row. Lower quarter wins ties (lower k).
    __shared__ float sd[1024];
    __shared__ int   si[1024];
    sd[tid] = best;
    si[tid] = bestk;
    __syncthreads();
    if (quarter == 0) {
#pragma unroll
        for (int q = 1; q < 4; ++q) {
            const float o = sd[q * 256 + row_local];
            const int  oi = si[q * 256 + row_local];
            if (o < best) { best = o; bestk = oi; }
        }
        out[n] = bestk;
    }
}

extern "C" void kernel_launch(void* const* d_in, const int* in_sizes, int n_in,
                              void* d_out, int out_size, void* d_ws, size_t ws_size,
                              hipStream_t stream) {
    const float* x  = (const float*)d_in[0];   // [16,64,64,64] fp32
    const float* cb = (const float*)d_in[1];   // [1024,64] fp32
    float* enorm = (float*)d_ws;               // 1024 floats scratch
    int*   out   = (int*)d_out;                // 65536 int32 indices

    enorm_kernel<<<dim3(K_CODES / 256), dim3(256), 0, stream>>>(cb, enorm);
    vq_kernel<<<dim3(65536 / 256), dim3(1024), 0, stream>>>(x, cb, enorm, out);
}

// Round 2
// 228.204 us; speedup vs baseline: 1.0585x; 1.0585x over previous
//
#include <hip/hip_runtime.h>

// VQ argmin: x [16,64,64,64] NCHW fp32, codebook [1024,64] fp32.
// N = 16*64*64 = 65536 rows (b,h,w), D=64 channels, K=1024 codes.
// dist = ||e_k||^2 - 2*x.e_k  (||x||^2 dropped: row-constant, argmin-invariant)
//
// R2: block = 256 threads = 64 rows x 4 K-quarters. xv[64] force-pinned in
// VGPRs (R1's VGPR_Count=36 proved the compiler demoted it -> reload stalls,
// VALUBusy 64%). Codebook index is wave-uniform -> scalar-load path.

#define K_CODES 1024
#define D_DIM   64
#define HW      4096   // 64*64

__global__ __launch_bounds__(256) void enorm_kernel(const float* __restrict__ cb,
                                                    float* __restrict__ enorm) {
    int k = blockIdx.x * 256 + threadIdx.x;   // grid = 4 x 256 -> 1024
    const float4* row = (const float4*)(cb + (size_t)k * D_DIM);
    float s = 0.f;
#pragma unroll
    for (int i = 0; i < D_DIM / 4; ++i) {
        float4 v = row[i];
        s = fmaf(v.x, v.x, s);
        s = fmaf(v.y, v.y, s);
        s = fmaf(v.z, v.z, s);
        s = fmaf(v.w, v.w, s);
    }
    enorm[k] = s;
}

__global__ __launch_bounds__(256, 4) void vq_kernel(const float* __restrict__ x,
                                                    const float* __restrict__ cb,
                                                    const float* __restrict__ enorm,
                                                    int* __restrict__ out) {
    const int tid = threadIdx.x;
    const int r = tid & 63;                                   // row within block
    const int quarter = __builtin_amdgcn_readfirstlane(tid >> 6);  // wave id, uniform
    const int n = blockIdx.x * 64 + r;
    const int b = n >> 12;          // n / 4096
    const int hw = n & (HW - 1);

    // Gather this row's 64 channels (stride HW floats). Coalesced across lanes.
    const float* xb = x + (size_t)b * D_DIM * HW + hw;
    float xv[D_DIM];
#pragma unroll
    for (int d = 0; d < D_DIM; ++d) xv[d] = xb[(size_t)d * HW];
    // Pin each element to a VGPR so the compiler cannot demote the array.
#pragma unroll
    for (int d = 0; d < D_DIM; ++d) asm("" : "+v"(xv[d]));

    float best = __builtin_inff();
    int bestk = 0;
    const int kbase = quarter * (K_CODES / 4);

#pragma unroll 1
    for (int kk = 0; kk < K_CODES / 4; kk += 4) {
        const int k = kbase + kk;                   // wave-uniform
        const float* __restrict__ e = cb + (size_t)k * D_DIM;
        float a0 = 0.f, a1 = 0.f, a2 = 0.f, a3 = 0.f;
#pragma unroll
        for (int d = 0; d < D_DIM; ++d) {
            const float xd = xv[d];
            a0 = fmaf(e[d],             xd, a0);
            a1 = fmaf(e[D_DIM + d],     xd, a1);
            a2 = fmaf(e[2 * D_DIM + d], xd, a2);
            a3 = fmaf(e[3 * D_DIM + d], xd, a3);
        }
        const float d0 = fmaf(-2.f, a0, enorm[k]);
        const float d1 = fmaf(-2.f, a1, enorm[k + 1]);
        const float d2 = fmaf(-2.f, a2, enorm[k + 2]);
        const float d3 = fmaf(-2.f, a3, enorm[k + 3]);
        // strict < and ascending k -> numpy argmin first-occurrence semantics
        if (d0 < best) { best = d0; bestk = k; }
        if (d1 < best) { best = d1; bestk = k + 1; }
        if (d2 < best) { best = d2; bestk = k + 2; }
        if (d3 < best) { best = d3; bestk = k + 3; }
    }

    // Combine the 4 K-quarters per row. Lower quarter wins ties (lower k).
    __shared__ float sd[256];
    __shared__ int   si[256];
    sd[tid] = best;
    si[tid] = bestk;
    __syncthreads();
    if (quarter == 0) {
#pragma unroll
        for (int q = 1; q < 4; ++q) {
            const float o = sd[q * 64 + r];
            const int  oi = si[q * 64 + r];
            if (o < best) { best = o; bestk = oi; }
        }
        out[n] = bestk;
    }
}

extern "C" void kernel_launch(void* const* d_in, const int* in_sizes, int n_in,
                              void* d_out, int out_size, void* d_ws, size_t ws_size,
                              hipStream_t stream) {
    const float* x  = (const float*)d_in[0];   // [16,64,64,64] fp32
    const float* cb = (const float*)d_in[1];   // [1024,64] fp32
    float* enorm = (float*)d_ws;               // 1024 floats scratch
    int*   out   = (int*)d_out;                // 65536 int32 indices

    enorm_kernel<<<dim3(K_CODES / 256), dim3(256), 0, stream>>>(cb, enorm);
    vq_kernel<<<dim3(65536 / 64), dim3(256), 0, stream>>>(x, cb, enorm, out);
}